// Round 1
// baseline (434.154 us; speedup 1.0000x reference)
//
#include <hip/hip_runtime.h>
#include <hip/hip_bf16.h>
#include <cstdint>

#define B_  16
#define S_  577
#define D_  768
#define H_  12
#define DH_ 64
#define SP  640           // padded S (multiple of 64)
#define M_  (B_*S_)       // 9232

typedef __attribute__((ext_vector_type(8))) short short8;
typedef __attribute__((ext_vector_type(4))) float f32x4;

static __device__ __forceinline__ unsigned short f2bf(float f) {
    uint32_t u = __builtin_bit_cast(uint32_t, f);
    uint32_t r = u + 0x7fffu + ((u >> 16) & 1u);
    return (unsigned short)(r >> 16);
}

// ---------------- Kernel 1: QKV projection GEMM ----------------
// C[m,n] = sum_k X[m,k] * W[n,k] + bias[n]   (x @ W^T + b)
// z=0 -> Q (scaled by 1/8), z=1 -> K, z=2 -> V (written transposed as Vt)
__global__ __launch_bounds__(256) void qkv_gemm(
    const float* __restrict__ X,
    const float* __restrict__ Wq, const float* __restrict__ Wk, const float* __restrict__ Wv,
    const float* __restrict__ bq, const float* __restrict__ bk, const float* __restrict__ bv,
    unsigned short* __restrict__ Qws, unsigned short* __restrict__ Kws,
    unsigned short* __restrict__ Vt)
{
    __shared__ unsigned short Als[128 * 40];   // [128][32] pad to 40 (80B stride, 16B-aligned)
    __shared__ unsigned short Bls[128 * 40];

    const int mt = blockIdx.x;      // 0..72
    const int nt = blockIdx.y;      // 0..5
    const int z  = blockIdx.z;      // 0..2
    const float* W    = (z == 0) ? Wq : (z == 1) ? Wk : Wv;
    const float* bias = (z == 0) ? bq : (z == 1) ? bk : bv;

    const int tid  = threadIdx.x;
    const int lane = tid & 63;
    const int wid  = tid >> 6;
    const int wm   = wid >> 1;      // 2x2 waves, each 64x64
    const int wn   = wid & 1;
    const int m0 = mt * 128, n0 = nt * 128;

    f32x4 acc[4][4] = {};

    for (int kk = 0; kk < 768; kk += 32) {
        // stage A (X) and B (W): 128 rows x 32 cols fp32 -> bf16, padded stride 40
        #pragma unroll
        for (int it = 0; it < 4; ++it) {
            int r  = (tid >> 3) + it * 32;    // 0..127
            int c4 = tid & 7;                 // float4 slot
            int m = m0 + r;
            float4 xv = make_float4(0.f, 0.f, 0.f, 0.f);
            if (m < M_) xv = *(const float4*)(X + (size_t)m * 768 + kk + c4 * 4);
            unsigned short pk[4] = { f2bf(xv.x), f2bf(xv.y), f2bf(xv.z), f2bf(xv.w) };
            *(uint2*)&Als[r * 40 + c4 * 4] = *(uint2*)pk;

            float4 wv4 = *(const float4*)(W + (size_t)(n0 + r) * 768 + kk + c4 * 4);
            unsigned short pk2[4] = { f2bf(wv4.x), f2bf(wv4.y), f2bf(wv4.z), f2bf(wv4.w) };
            *(uint2*)&Bls[r * 40 + c4 * 4] = *(uint2*)pk2;
        }
        __syncthreads();

        short8 af[4], bfr[4];
        #pragma unroll
        for (int i = 0; i < 4; ++i) {
            int ra = wm * 64 + i * 16 + (lane & 15);
            af[i]  = *(const short8*)&Als[ra * 40 + (lane >> 4) * 8];
            int rb = wn * 64 + i * 16 + (lane & 15);
            bfr[i] = *(const short8*)&Bls[rb * 40 + (lane >> 4) * 8];
        }
        #pragma unroll
        for (int i = 0; i < 4; ++i)
            #pragma unroll
            for (int j = 0; j < 4; ++j)
                acc[i][j] = __builtin_amdgcn_mfma_f32_16x16x32_bf16(af[i], bfr[j], acc[i][j], 0, 0, 0);
        __syncthreads();
    }

    // epilogue: bias, (scale for Q), convert, scatter to ws
    float bs[4];
    #pragma unroll
    for (int j = 0; j < 4; ++j) bs[j] = bias[n0 + wn * 64 + j * 16 + (lane & 15)];

    #pragma unroll
    for (int i = 0; i < 4; ++i) {
        #pragma unroll
        for (int j = 0; j < 4; ++j) {
            int n = n0 + wn * 64 + j * 16 + (lane & 15);
            #pragma unroll
            for (int r = 0; r < 4; ++r) {
                int m = m0 + wm * 64 + i * 16 + (lane >> 4) * 4 + r;
                if (m >= M_) continue;
                float val = acc[i][j][r] + bs[j];
                int b = m / 577;
                int s = m - b * 577;
                if (z == 0) {
                    Qws[((size_t)b * SP + s) * 768 + n] = f2bf(val * 0.125f);
                } else if (z == 1) {
                    Kws[((size_t)b * SP + s) * 768 + n] = f2bf(val);
                } else {
                    int h = n >> 6, dh = n & 63;
                    Vt[(((size_t)b * H_ + h) * DH_ + dh) * SP + s] = f2bf(val);
                }
            }
        }
    }
}

// ---------------- Kernel 2: fused scores + softmax + probs-write + PV ----------------
// block: 256 threads (4 waves); tile: 16 queries x all 640 (padded) keys for one (b,h)
__global__ __launch_bounds__(256) void attn(
    const unsigned short* __restrict__ Qws, const unsigned short* __restrict__ Kws,
    const unsigned short* __restrict__ Vt,
    float* __restrict__ ctx, float* __restrict__ probs)
{
    __shared__ float          sc[16 * 648];       // scores (fp32), stride 648
    __shared__ unsigned short P[16 * 648];        // probs (bf16), stride 648
    __shared__ unsigned short Qls[16 * 72];       // Q tile, padded stride 72
    __shared__ unsigned short Kls[64 * 72];       // K chunk, padded stride 72
    __shared__ float          redbuf[16 * 16];
    __shared__ float          rowm[16], rowinv[16];

    const int qt  = blockIdx.x;    // 0..36
    const int h   = blockIdx.y;
    const int b   = blockIdx.z;
    const int tid = threadIdx.x;
    const int lane = tid & 63;
    const int wid  = tid >> 6;
    const int q0 = qt * 16;

    // stage Q tile: 16 rows x 64 cols (bf16)
    {
        int r = tid >> 4, c4 = tid & 15;
        *(uint2*)&Qls[r * 72 + c4 * 4] =
            *(const uint2*)&Qws[((size_t)b * SP + q0 + r) * 768 + h * 64 + c4 * 4];
    }
    __syncthreads();

    short8 aq0 = *(const short8*)&Qls[(lane & 15) * 72 + (lane >> 4) * 8];
    short8 aq1 = *(const short8*)&Qls[(lane & 15) * 72 + 32 + (lane >> 4) * 8];

    // QK^T: 10 chunks of 64 keys
    for (int c = 0; c < 10; ++c) {
        __syncthreads();
        #pragma unroll
        for (int it = 0; it < 4; ++it) {
            int slot = tid + it * 256;         // 1024 uint2 slots
            int r = slot >> 4, c4 = slot & 15;
            *(uint2*)&Kls[r * 72 + c4 * 4] =
                *(const uint2*)&Kws[((size_t)b * SP + c * 64 + r) * 768 + h * 64 + c4 * 4];
        }
        __syncthreads();

        short8 bk0 = *(const short8*)&Kls[(wid * 16 + (lane & 15)) * 72 + (lane >> 4) * 8];
        short8 bk1 = *(const short8*)&Kls[(wid * 16 + (lane & 15)) * 72 + 32 + (lane >> 4) * 8];
        f32x4 s4 = {};
        s4 = __builtin_amdgcn_mfma_f32_16x16x32_bf16(aq0, bk0, s4, 0, 0, 0);
        s4 = __builtin_amdgcn_mfma_f32_16x16x32_bf16(aq1, bk1, s4, 0, 0, 0);

        int key = c * 64 + wid * 16 + (lane & 15);
        #pragma unroll
        for (int r = 0; r < 4; ++r) {
            int qr = (lane >> 4) * 4 + r;
            sc[qr * 648 + key] = (key < S_) ? s4[r] : -1e30f;
        }
    }
    __syncthreads();

    // softmax over each of the 16 rows (16 threads per row)
    {
        int r = tid >> 4, c0 = tid & 15;
        float m = -1e30f;
        for (int c = c0; c < SP; c += 16) m = fmaxf(m, sc[r * 648 + c]);
        redbuf[r * 16 + c0] = m;
        __syncthreads();
        if (tid < 16) {
            float mm = -1e30f;
            #pragma unroll
            for (int i = 0; i < 16; ++i) mm = fmaxf(mm, redbuf[tid * 16 + i]);
            rowm[tid] = mm;
        }
        __syncthreads();
        float mm = rowm[r];
        float ssum = 0.f;
        for (int c = c0; c < SP; c += 16) {
            float e = __expf(sc[r * 648 + c] - mm);
            sc[r * 648 + c] = e;
            ssum += e;
        }
        __syncthreads();           // redbuf reuse hazard
        redbuf[r * 16 + c0] = ssum;
        __syncthreads();
        if (tid < 16) {
            float s = 0.f;
            #pragma unroll
            for (int i = 0; i < 16; ++i) s += redbuf[tid * 16 + i];
            rowinv[tid] = 1.0f / s;
        }
        __syncthreads();
        // bf16 P tile for PV
        float inv = rowinv[r];
        for (int c = c0; c < SP; c += 16)
            P[r * 648 + c] = f2bf(sc[r * 648 + c] * inv);
    }

    // coalesced probs write (fp32)
    for (int r = 0; r < 16; ++r) {
        int q = q0 + r;
        if (q >= S_) break;
        float inv = rowinv[r];
        size_t base = (((size_t)b * H_ + h) * S_ + q) * S_;
        for (int c = tid; c < S_; c += 256)
            probs[base + c] = sc[r * 648 + c] * inv;
    }
    __syncthreads();

    // PV: each wave computes one 16-wide d-slice; K-loop over 640 padded keys
    {
        f32x4 oc = {};
        const unsigned short* vbase =
            Vt + (((size_t)b * H_ + h) * DH_ + wid * 16 + (lane & 15)) * SP + (lane >> 4) * 8;
        for (int kk = 0; kk < SP; kk += 32) {
            short8 ap = *(const short8*)&P[(lane & 15) * 648 + kk + (lane >> 4) * 8];
            short8 bv = *(const short8*)(vbase + kk);
            oc = __builtin_amdgcn_mfma_f32_16x16x32_bf16(ap, bv, oc, 0, 0, 0);
        }
        #pragma unroll
        for (int r = 0; r < 4; ++r) {
            int q = q0 + (lane >> 4) * 4 + r;
            if (q < S_)
                ctx[((size_t)b * S_ + q) * 768 + h * 64 + wid * 16 + (lane & 15)] = oc[r];
        }
    }
}

extern "C" void kernel_launch(void* const* d_in, const int* in_sizes, int n_in,
                              void* d_out, int out_size, void* d_ws, size_t ws_size,
                              hipStream_t stream) {
    const float* X  = (const float*)d_in[0];
    const float* Wq = (const float*)d_in[1];
    const float* bq = (const float*)d_in[2];
    const float* Wk = (const float*)d_in[3];
    const float* bk = (const float*)d_in[4];
    const float* Wv = (const float*)d_in[5];
    const float* bv = (const float*)d_in[6];

    float* ctx   = (float*)d_out;
    float* probs = ctx + (size_t)B_ * S_ * D_;

    unsigned short* Qws = (unsigned short*)d_ws;
    unsigned short* Kws = Qws + (size_t)B_ * SP * D_;
    unsigned short* Vt  = Kws + (size_t)B_ * SP * D_;
    size_t ws_needed = (size_t)B_ * SP * D_ * 2 * 3;   // ~47.2 MB

    hipMemsetAsync(d_ws, 0, ws_needed, stream);

    dim3 g1(73, 6, 3);
    qkv_gemm<<<g1, 256, 0, stream>>>(X, Wq, Wk, Wv, bq, bk, bv, Qws, Kws, Vt);

    dim3 g2(37, H_, B_);
    attn<<<g2, 256, 0, stream>>>(Qws, Kws, Vt, ctx, probs);
}

// Round 2
// 259.906 us; speedup vs baseline: 1.6704x; 1.6704x over previous
//
#include <hip/hip_runtime.h>
#include <hip/hip_bf16.h>
#include <cstdint>

#define B_  16
#define S_  577
#define D_  768
#define H_  12
#define SP  640           // padded S
#define M_  (B_*S_)       // 9232
#define MP  9344          // padded M (73*128)
#define N_  2304          // combined QKV output dim

typedef __attribute__((ext_vector_type(8))) short short8;
typedef __attribute__((ext_vector_type(4))) float f32x4;

static __device__ __forceinline__ unsigned short f2bf(float f) {
    uint32_t u = __builtin_bit_cast(uint32_t, f);
    uint32_t r = u + 0x7fffu + ((u >> 16) & 1u);
    return (unsigned short)(r >> 16);
}
static __device__ __forceinline__ float bf2f(unsigned short u) {
    uint32_t x = ((uint32_t)u) << 16;
    return __builtin_bit_cast(float, x);
}

typedef unsigned int u32;
typedef __attribute__((address_space(3))) u32 lds_u32;
typedef __attribute__((address_space(1))) const u32 gbl_u32;
static __device__ __forceinline__ void gll16(const void* g, void* l) {
    __builtin_amdgcn_global_load_lds((gbl_u32*)g, (lds_u32*)l, 16, 0, 0);
}

// ---------- prep: fp32 -> bf16 conversion of X and W; zero S-pad regions ----------
__global__ __launch_bounds__(256) void prep(
    const float* __restrict__ X,
    const float* __restrict__ Wq, const float* __restrict__ Wk, const float* __restrict__ Wv,
    unsigned short* __restrict__ Xb, unsigned short* __restrict__ Wb,
    unsigned short* __restrict__ Qws, unsigned short* __restrict__ Kws,
    unsigned short* __restrict__ Vt)
{
    const int NT1 = MP * 192;          // f4 slots for Xb
    const int NT2 = N_ * 192;          // f4 slots for Wb
    const int NP  = 16 * 63 * 768;     // pad shorts per tensor
    const int total = NT1 + NT2 + 3 * NP;
    const int stride = gridDim.x * 256;
    for (int i = blockIdx.x * 256 + threadIdx.x; i < total; i += stride) {
        if (i < NT1) {
            int row = i / 192, c4 = i - row * 192;
            uint2 out;
            if (row < M_) {
                float4 v = *(const float4*)(X + (size_t)row * 768 + c4 * 4);
                unsigned short p[4] = { f2bf(v.x), f2bf(v.y), f2bf(v.z), f2bf(v.w) };
                out = *(uint2*)p;
            } else out = make_uint2(0u, 0u);
            *(uint2*)(Xb + (size_t)row * 768 + c4 * 4) = out;
        } else if (i < NT1 + NT2) {
            int j = i - NT1;
            int row = j / 192, c4 = j - row * 192;
            const float* src = (row < 768) ? (Wq + (size_t)row * 768)
                             : (row < 1536) ? (Wk + (size_t)(row - 768) * 768)
                                            : (Wv + (size_t)(row - 1536) * 768);
            float4 v = *(const float4*)(src + c4 * 4);
            unsigned short p[4] = { f2bf(v.x), f2bf(v.y), f2bf(v.z), f2bf(v.w) };
            *(uint2*)(Wb + (size_t)row * 768 + c4 * 4) = *(uint2*)p;
        } else {
            int j = i - NT1 - NT2;
            int t = j / NP, r2 = j - t * NP;
            if (t < 2) {
                int b = r2 / (63 * 768); int rem = r2 - b * 63 * 768;
                int s = 577 + rem / 768; int col = rem % 768;
                (t == 0 ? Qws : Kws)[((size_t)b * SP + s) * 768 + col] = 0;
            } else {
                int row = r2 / 63; int s = 577 + (r2 - row * 63);
                Vt[(size_t)row * SP + s] = 0;
            }
        }
    }
}

// ---------- qkv_gemm: C[m,n] = sum_k Xb[m,k]*Wb[n,k] + bias ----------
// n<768 -> Q (scaled 0.125), n<1536 -> K, else V (transposed into Vt)
__global__ __launch_bounds__(256) void qkv_gemm(
    const unsigned short* __restrict__ Xb, const unsigned short* __restrict__ Wb,
    const float* __restrict__ bq, const float* __restrict__ bk, const float* __restrict__ bv,
    unsigned short* __restrict__ Qws, unsigned short* __restrict__ Kws,
    unsigned short* __restrict__ Vt)
{
    __shared__ unsigned short Als[128 * 32];
    __shared__ unsigned short Bls[128 * 32];

    const int mt = blockIdx.x, nt = blockIdx.y;
    const int tid = threadIdx.x, lane = tid & 63, wid = tid >> 6;
    const int wm = wid >> 1, wn = wid & 1;
    const int m0 = mt * 128, n0 = nt * 128;
    const int srow = lane >> 2;            // 0..15
    const int scol = (lane & 3) * 8;       // shorts

    f32x4 acc[4][4] = {};

    for (int kk = 0; kk < 768; kk += 32) {
        __syncthreads();
        const unsigned short* gA = Xb + (size_t)(m0 + wid * 32 + srow) * 768 + kk + scol;
        const unsigned short* gB = Wb + (size_t)(n0 + wid * 32 + srow) * 768 + kk + scol;
        gll16(gA,            &Als[(wid * 32 + 0 ) * 32]);
        gll16(gA + 16 * 768, &Als[(wid * 32 + 16) * 32]);
        gll16(gB,            &Bls[(wid * 32 + 0 ) * 32]);
        gll16(gB + 16 * 768, &Bls[(wid * 32 + 16) * 32]);
        __syncthreads();

        short8 af[4], bf[4];
        #pragma unroll
        for (int i = 0; i < 4; ++i)
            af[i] = *(const short8*)&Als[(wm * 64 + i * 16 + (lane & 15)) * 32 + (lane >> 4) * 8];
        #pragma unroll
        for (int j = 0; j < 4; ++j)
            bf[j] = *(const short8*)&Bls[(wn * 64 + j * 16 + (lane & 15)) * 32 + (lane >> 4) * 8];
        #pragma unroll
        for (int i = 0; i < 4; ++i)
            #pragma unroll
            for (int j = 0; j < 4; ++j)
                acc[i][j] = __builtin_amdgcn_mfma_f32_16x16x32_bf16(af[i], bf[j], acc[i][j], 0, 0, 0);
    }

    #pragma unroll
    for (int j = 0; j < 4; ++j) {
        int n = n0 + wn * 64 + j * 16 + (lane & 15);
        float bias = (n < 768) ? bq[n] : (n < 1536) ? bk[n - 768] : bv[n - 1536];
        #pragma unroll
        for (int i = 0; i < 4; ++i) {
            #pragma unroll
            for (int r = 0; r < 4; ++r) {
                int m = m0 + wm * 64 + i * 16 + (lane >> 4) * 4 + r;
                if (m >= M_) continue;
                int b = m / 577;
                int s = m - b * 577;
                float val = acc[i][j][r] + bias;
                if (n < 768) {
                    Qws[((size_t)b * SP + s) * 768 + n] = f2bf(val * 0.125f);
                } else if (n < 1536) {
                    Kws[((size_t)b * SP + s) * 768 + (n - 768)] = f2bf(val);
                } else {
                    int nn = n - 1536;
                    Vt[((size_t)(b * H_ + (nn >> 6)) * 64 + (nn & 63)) * SP + s] = f2bf(val);
                }
            }
        }
    }
}

// ---------- attn: scores + softmax + probs write + PV, 16 queries per block ----------
__global__ __launch_bounds__(256) void attn(
    const unsigned short* __restrict__ Qws, const unsigned short* __restrict__ Kws,
    const unsigned short* __restrict__ Vt,
    float* __restrict__ ctx, float* __restrict__ probs)
{
    __shared__ unsigned short sc[16 * 672];   // bf16 scores -> e-values, 21.5 KB
    __shared__ float rowinv[16];

    const int qt = blockIdx.x, h = blockIdx.y, b = blockIdx.z;
    const int tid = threadIdx.x, lane = tid & 63, wid = tid >> 6;
    const int l15 = lane & 15, g = lane >> 4;
    const int q0 = qt * 16;

    // Q fragments straight from global (L2-resident)
    const unsigned short* qb = Qws + ((size_t)b * SP + q0 + l15) * 768 + h * 64 + g * 8;
    short8 aq0 = *(const short8*)qb;
    short8 aq1 = *(const short8*)(qb + 32);

    // QK^T: 10 chunks of 64 keys, K fragments from global, no barriers
    const unsigned short* kbase = Kws + ((size_t)b * SP + wid * 16 + l15) * 768 + h * 64 + g * 8;
    #pragma unroll
    for (int c = 0; c < 10; ++c) {
        const unsigned short* kb = kbase + (size_t)c * 64 * 768;
        short8 bk0 = *(const short8*)kb;
        short8 bk1 = *(const short8*)(kb + 32);
        f32x4 s4 = {};
        s4 = __builtin_amdgcn_mfma_f32_16x16x32_bf16(aq0, bk0, s4, 0, 0, 0);
        s4 = __builtin_amdgcn_mfma_f32_16x16x32_bf16(aq1, bk1, s4, 0, 0, 0);
        int key = c * 64 + wid * 16 + l15;
        #pragma unroll
        for (int r = 0; r < 4; ++r)
            sc[(g * 4 + r) * 672 + key] = (key < S_) ? f2bf(s4[r]) : (unsigned short)0xFF80u; // -inf
    }
    __syncthreads();

    // softmax: 16 threads per row, wave-internal shuffles only
    const int r = tid >> 4, c0 = tid & 15;
    unsigned short* row = &sc[r * 672];
    float m = -1e30f;
    #pragma unroll
    for (int i = 0; i < 5; ++i) {
        short8 v = *(const short8*)&row[(c0 + 16 * i) * 8];
        #pragma unroll
        for (int jj = 0; jj < 8; ++jj) m = fmaxf(m, bf2f((unsigned short)v[jj]));
    }
    #pragma unroll
    for (int o = 8; o; o >>= 1) m = fmaxf(m, __shfl_xor(m, o));

    float ssum = 0.f;
    #pragma unroll
    for (int i = 0; i < 5; ++i) {
        short8 v = *(const short8*)&row[(c0 + 16 * i) * 8];
        short8 w;
        #pragma unroll
        for (int jj = 0; jj < 8; ++jj) {
            float e = __expf(bf2f((unsigned short)v[jj]) - m);
            ssum += e;
            w[jj] = (short)f2bf(e);
        }
        *(short8*)&row[(c0 + 16 * i) * 8] = w;
    }
    #pragma unroll
    for (int o = 8; o; o >>= 1) ssum += __shfl_xor(ssum, o);
    float inv = 1.0f / ssum;
    if (c0 == 0) rowinv[r] = inv;

    // probs write (fp32, vectorized, coalesced per row)
    int q = q0 + r;
    if (q < S_) {
        float* prow = probs + ((size_t)(b * H_ + h) * S_ + q) * S_;
        #pragma unroll
        for (int i = 0; i < 5; ++i) {
            int ch = c0 + 16 * i;
            short8 v = *(const short8*)&row[ch * 8];
            if (ch < 72) {
                float4 o0, o1;
                o0.x = bf2f((unsigned short)v[0]) * inv; o0.y = bf2f((unsigned short)v[1]) * inv;
                o0.z = bf2f((unsigned short)v[2]) * inv; o0.w = bf2f((unsigned short)v[3]) * inv;
                o1.x = bf2f((unsigned short)v[4]) * inv; o1.y = bf2f((unsigned short)v[5]) * inv;
                o1.z = bf2f((unsigned short)v[6]) * inv; o1.w = bf2f((unsigned short)v[7]) * inv;
                *(float4*)&prow[ch * 8]     = o0;
                *(float4*)&prow[ch * 8 + 4] = o1;
            } else if (ch == 72) {
                prow[576] = bf2f((unsigned short)v[0]) * inv;
            }
        }
    }
    __syncthreads();

    // PV: wave wid owns d-slice [wid*16, wid*16+16); V^T fragments from global
    f32x4 oc = {};
    const unsigned short* vb = Vt + ((size_t)(b * H_ + h) * 64 + wid * 16 + l15) * SP + g * 8;
    const unsigned short* pb = &sc[l15 * 672 + g * 8];
    #pragma unroll
    for (int kk = 0; kk < SP; kk += 32) {
        short8 ap = *(const short8*)(pb + kk);
        short8 bv = *(const short8*)(vb + kk);
        oc = __builtin_amdgcn_mfma_f32_16x16x32_bf16(ap, bv, oc, 0, 0, 0);
    }
    #pragma unroll
    for (int rr = 0; rr < 4; ++rr) {
        int qr = g * 4 + rr;
        int qq = q0 + qr;
        if (qq < S_)
            ctx[((size_t)b * S_ + qq) * D_ + h * 64 + wid * 16 + l15] = oc[rr] * rowinv[qr];
    }
}

extern "C" void kernel_launch(void* const* d_in, const int* in_sizes, int n_in,
                              void* d_out, int out_size, void* d_ws, size_t ws_size,
                              hipStream_t stream) {
    const float* X  = (const float*)d_in[0];
    const float* Wq = (const float*)d_in[1];
    const float* bq = (const float*)d_in[2];
    const float* Wk = (const float*)d_in[3];
    const float* bk = (const float*)d_in[4];
    const float* Wv = (const float*)d_in[5];
    const float* bv = (const float*)d_in[6];

    float* ctx   = (float*)d_out;
    float* probs = ctx + (size_t)B_ * S_ * D_;

    // bf16 staging of X/W lives in the (later overwritten) probs region of d_out
    unsigned short* Xb = (unsigned short*)probs;            // 14.35 MB
    unsigned short* Wb = Xb + (size_t)MP * 768;             //  3.54 MB  (<< 255 MB region)

    unsigned short* Qws = (unsigned short*)d_ws;            // [16][640][768] bf16
    unsigned short* Kws = Qws + (size_t)B_ * SP * D_;
    unsigned short* Vt  = Kws + (size_t)B_ * SP * D_;       // [16*12*64][640] bf16

    prep<<<dim3(2048), 256, 0, stream>>>(X, Wq, Wk, Wv, Xb, Wb, Qws, Kws, Vt);
    qkv_gemm<<<dim3(73, 18), 256, 0, stream>>>(Xb, Wb, bq, bk, bv, Qws, Kws, Vt);
    attn<<<dim3(37, H_, B_), 256, 0, stream>>>(Qws, Kws, Vt, ctx, probs);
}

// Round 3
// 215.301 us; speedup vs baseline: 2.0165x; 1.2072x over previous
//
#include <hip/hip_runtime.h>
#include <hip/hip_bf16.h>
#include <cstdint>

#define B_  16
#define S_  577
#define D_  768
#define H_  12
#define SP  640           // padded S
#define M_  (B_*S_)       // 9232
#define MP  9344          // padded M (73*128)
#define N_  2304          // combined QKV output dim
#define SCS 664           // sc LDS stride in shorts (odd multiple of 8 -> good bank spread)

typedef __attribute__((ext_vector_type(8))) short short8;
typedef __attribute__((ext_vector_type(4))) float f32x4;

static __device__ __forceinline__ unsigned short f2bf(float f) {
    uint32_t u = __builtin_bit_cast(uint32_t, f);
    uint32_t r = u + 0x7fffu + ((u >> 16) & 1u);
    return (unsigned short)(r >> 16);
}
static __device__ __forceinline__ float bf2f(unsigned short u) {
    uint32_t x = ((uint32_t)u) << 16;
    return __builtin_bit_cast(float, x);
}

typedef unsigned int u32;
typedef __attribute__((address_space(3))) u32 lds_u32;
typedef __attribute__((address_space(1))) const u32 gbl_u32;
static __device__ __forceinline__ void gll16(const void* g, void* l) {
    __builtin_amdgcn_global_load_lds((gbl_u32*)g, (lds_u32*)l, 16, 0, 0);
}

// Fragment layouts (shorts), d = within-head dim (0..63):
//  Qf: ((((b*40+qc)*12+h)*2+dh)*512) + ql*32 + dg*8 + db      q=qc*16+ql, d=dh*32+dg*8+db
//  Kf: ((((b*12+h)*10+c)*4+kq)*2+dh)*512 + kl*32 + dg*8 + db  key=c*64+kq*16+kl
//  Vf: (((b*12+h)*20+kk)*4+wq)*512 + dl*32 + kg*8 + kb        key=kk*32+kg*8+kb, d=wq*16+dl
// Each attn wave fragment load = contiguous 1KB.

// ---------- prep: fp32 -> bf16 conversion of X (with zero pad rows) and W ----------
__global__ __launch_bounds__(256) void prep(
    const float* __restrict__ X,
    const float* __restrict__ Wq, const float* __restrict__ Wk, const float* __restrict__ Wv,
    unsigned short* __restrict__ Xb, unsigned short* __restrict__ Wb)
{
    const int NT1 = MP * 192;
    const int NT2 = N_ * 192;
    const int total = NT1 + NT2;
    const int stride = gridDim.x * 256;
    for (int i = blockIdx.x * 256 + threadIdx.x; i < total; i += stride) {
        if (i < NT1) {
            int row = i / 192, c4 = i - row * 192;
            uint2 out = make_uint2(0u, 0u);
            if (row < M_) {
                float4 v = *(const float4*)(X + (size_t)row * 768 + c4 * 4);
                unsigned short p[4] = { f2bf(v.x), f2bf(v.y), f2bf(v.z), f2bf(v.w) };
                out = *(uint2*)p;
            }
            *(uint2*)(Xb + (size_t)row * 768 + c4 * 4) = out;
        } else {
            int j = i - NT1;
            int row = j / 192, c4 = j - row * 192;
            const float* src = (row < 768) ? (Wq + (size_t)row * 768)
                             : (row < 1536) ? (Wk + (size_t)(row - 768) * 768)
                                            : (Wv + (size_t)(row - 1536) * 768);
            float4 v = *(const float4*)(src + c4 * 4);
            unsigned short p[4] = { f2bf(v.x), f2bf(v.y), f2bf(v.z), f2bf(v.w) };
            *(uint2*)(Wb + (size_t)row * 768 + c4 * 4) = *(uint2*)p;
        }
    }
}

// ---------- qkv_gemm: BK=64, XOR-swizzled LDS via pre-swizzled gll16 source ----------
__global__ __launch_bounds__(256) void qkv_gemm(
    const unsigned short* __restrict__ Xb, const unsigned short* __restrict__ Wb,
    const float* __restrict__ bq, const float* __restrict__ bk, const float* __restrict__ bv,
    unsigned short* __restrict__ Qf, unsigned short* __restrict__ Kf,
    unsigned short* __restrict__ Vf)
{
    __shared__ unsigned short Als[128 * 64];
    __shared__ unsigned short Bls[128 * 64];

    const int mt = blockIdx.x, nt = blockIdx.y;
    const int tid = threadIdx.x, lane = tid & 63, wid = tid >> 6;
    const int wm = wid >> 1, wn = wid & 1;
    const int m0 = mt * 128, n0 = nt * 128;
    const int prow = lane >> 3;     // 0..7 row within 8-row staging round
    const int pc8  = lane & 7;      // physical 16B slot

    f32x4 acc[4][4] = {};

    for (int kk = 0; kk < 768; kk += 64) {
        __syncthreads();
        #pragma unroll
        for (int t = 0; t < 4; ++t) {
            int row  = wid * 32 + t * 8 + prow;
            int scol = ((pc8 ^ (row & 7)) * 8);    // pre-swizzled source column (shorts)
            gll16(Xb + (size_t)(m0 + row) * 768 + kk + scol, &Als[(wid * 32 + t * 8) * 64]);
            gll16(Wb + (size_t)(n0 + row) * 768 + kk + scol, &Bls[(wid * 32 + t * 8) * 64]);
        }
        __syncthreads();

        #pragma unroll
        for (int ks = 0; ks < 2; ++ks) {
            short8 af[4], bfv[4];
            #pragma unroll
            for (int i = 0; i < 4; ++i) {
                int row = wm * 64 + i * 16 + (lane & 15);
                af[i] = *(const short8*)&Als[row * 64 + (((ks * 4 + (lane >> 4)) ^ (row & 7)) * 8)];
            }
            #pragma unroll
            for (int j = 0; j < 4; ++j) {
                int row = wn * 64 + j * 16 + (lane & 15);
                bfv[j] = *(const short8*)&Bls[row * 64 + (((ks * 4 + (lane >> 4)) ^ (row & 7)) * 8)];
            }
            #pragma unroll
            for (int i = 0; i < 4; ++i)
                #pragma unroll
                for (int j = 0; j < 4; ++j)
                    acc[i][j] = __builtin_amdgcn_mfma_f32_16x16x32_bf16(af[i], bfv[j], acc[i][j], 0, 0, 0);
        }
    }

    // epilogue: bias, scale, scatter into fragment layouts
    #pragma unroll
    for (int j = 0; j < 4; ++j) {
        int n = n0 + wn * 64 + j * 16 + (lane & 15);
        float bias = (n < 768) ? bq[n] : (n < 1536) ? bk[n - 768] : bv[n - 1536];
        int nn  = (n < 768) ? n : (n < 1536) ? n - 768 : n - 1536;
        int hh  = nn >> 6, dwh = nn & 63;
        #pragma unroll
        for (int i = 0; i < 4; ++i) {
            #pragma unroll
            for (int r = 0; r < 4; ++r) {
                int m = m0 + wm * 64 + i * 16 + (lane >> 4) * 4 + r;
                if (m >= M_) continue;
                int b = m / 577;
                int s = m - b * 577;
                float val = acc[i][j][r] + bias;
                size_t bh = (size_t)b * 12 + hh;
                if (n < 768) {
                    size_t off = (((size_t)(b * 40 + (s >> 4)) * 12 + hh) * 2 + (dwh >> 5)) * 512
                               + (s & 15) * 32 + ((dwh >> 3) & 3) * 8 + (dwh & 7);
                    Qf[off] = f2bf(val * 0.125f);
                } else if (n < 1536) {
                    size_t off = ((bh * 10 + (s >> 6)) * 8 + ((s >> 4) & 3) * 2 + (dwh >> 5)) * 512
                               + (s & 15) * 32 + ((dwh >> 3) & 3) * 8 + (dwh & 7);
                    Kf[off] = f2bf(val);
                } else {
                    size_t off = ((bh * 20 + (s >> 5)) * 4 + (dwh >> 4)) * 512
                               + (dwh & 15) * 32 + ((s >> 3) & 3) * 8 + (s & 7);
                    Vf[off] = f2bf(val);
                }
            }
        }
    }
}

// ---------- attn: coalesced fragment loads, XCD-swizzled grid ----------
__global__ __launch_bounds__(256) void attn(
    const unsigned short* __restrict__ Qf, const unsigned short* __restrict__ Kf,
    const unsigned short* __restrict__ Vf,
    float* __restrict__ ctx, float* __restrict__ probs)
{
    __shared__ unsigned short sc[16 * SCS];
    __shared__ float rowinv[16];

    const int wg  = blockIdx.x;                 // 7104 = 8 * 888, bijective XCD swizzle
    const int idx = (wg & 7) * 888 + (wg >> 3);
    const int bh  = idx / 37;
    const int qt  = idx - bh * 37;
    const int h   = bh % 12, b = bh / 12;

    const int tid = threadIdx.x, lane = tid & 63, wid = tid >> 6;
    const int l15 = lane & 15, g = lane >> 4;
    const int q0 = qt * 16;
    const int lofs = l15 * 32 + g * 8;

    // Q fragments: contiguous 1KB per wave
    const unsigned short* qb = Qf + ((size_t)(b * 40 + qt) * 12 + h) * 1024 + lofs;
    short8 aq0 = *(const short8*)qb;
    short8 aq1 = *(const short8*)(qb + 512);

    // QK^T over 10 chunks of 64 keys
    const unsigned short* kb0 = Kf + (size_t)bh * 40960 + wid * 1024 + lofs;
    #pragma unroll
    for (int c = 0; c < 10; ++c) {
        const unsigned short* kb = kb0 + c * 4096;
        short8 bk0 = *(const short8*)kb;
        short8 bk1 = *(const short8*)(kb + 512);
        f32x4 s4 = {};
        s4 = __builtin_amdgcn_mfma_f32_16x16x32_bf16(aq0, bk0, s4, 0, 0, 0);
        s4 = __builtin_amdgcn_mfma_f32_16x16x32_bf16(aq1, bk1, s4, 0, 0, 0);
        int key = c * 64 + wid * 16 + l15;
        #pragma unroll
        for (int r = 0; r < 4; ++r)
            sc[(g * 4 + r) * SCS + key] = (key < S_) ? f2bf(s4[r]) : (unsigned short)0xFF80u; // -inf
    }
    __syncthreads();

    // softmax: 16 threads per row, wave-internal shuffles
    const int r = tid >> 4, c0 = tid & 15;
    unsigned short* row = &sc[r * SCS];
    float m = -1e30f;
    #pragma unroll
    for (int i = 0; i < 5; ++i) {
        short8 v = *(const short8*)&row[(c0 + 16 * i) * 8];
        #pragma unroll
        for (int jj = 0; jj < 8; ++jj) m = fmaxf(m, bf2f((unsigned short)v[jj]));
    }
    #pragma unroll
    for (int o = 8; o; o >>= 1) m = fmaxf(m, __shfl_xor(m, o));

    float ssum = 0.f;
    #pragma unroll
    for (int i = 0; i < 5; ++i) {
        short8 v = *(const short8*)&row[(c0 + 16 * i) * 8];
        short8 w;
        #pragma unroll
        for (int jj = 0; jj < 8; ++jj) {
            float e = __expf(bf2f((unsigned short)v[jj]) - m);
            ssum += e;
            w[jj] = (short)f2bf(e);
        }
        *(short8*)&row[(c0 + 16 * i) * 8] = w;
    }
    #pragma unroll
    for (int o = 8; o; o >>= 1) ssum += __shfl_xor(ssum, o);
    float inv = 1.0f / ssum;
    if (c0 == 0) rowinv[r] = inv;
    __syncthreads();

    // probs write after the barrier: stores drain under PV's MFMA
    int q = q0 + r;
    if (q < S_) {
        float* prow = probs + ((size_t)bh * S_ + q) * S_;
        #pragma unroll
        for (int i = 0; i < 5; ++i) {
            int ch = c0 + 16 * i;
            short8 v = *(const short8*)&row[ch * 8];
            if (ch < 72) {
                float4 o0, o1;
                o0.x = bf2f((unsigned short)v[0]) * inv; o0.y = bf2f((unsigned short)v[1]) * inv;
                o0.z = bf2f((unsigned short)v[2]) * inv; o0.w = bf2f((unsigned short)v[3]) * inv;
                o1.x = bf2f((unsigned short)v[4]) * inv; o1.y = bf2f((unsigned short)v[5]) * inv;
                o1.z = bf2f((unsigned short)v[6]) * inv; o1.w = bf2f((unsigned short)v[7]) * inv;
                *(float4*)&prow[ch * 8]     = o0;
                *(float4*)&prow[ch * 8 + 4] = o1;
            } else if (ch == 72) {
                prow[576] = bf2f((unsigned short)v[0]) * inv;
            }
        }
    }

    // PV: wave wid owns d-slice [wid*16, wid*16+16)
    f32x4 oc = {};
    const unsigned short* vb0 = Vf + (size_t)bh * 40960 + wid * 512 + lofs;
    const unsigned short* pb  = &sc[l15 * SCS + g * 8];
    #pragma unroll
    for (int kk = 0; kk < 20; ++kk) {
        short8 ap = *(const short8*)(pb + kk * 32);
        short8 bv = *(const short8*)(vb0 + kk * 2048);
        oc = __builtin_amdgcn_mfma_f32_16x16x32_bf16(ap, bv, oc, 0, 0, 0);
    }
    #pragma unroll
    for (int rr = 0; rr < 4; ++rr) {
        int qr = g * 4 + rr;
        int qq = q0 + qr;
        if (qq < S_)
            ctx[((size_t)b * S_ + qq) * D_ + h * 64 + wid * 16 + l15] = oc[rr] * rowinv[qr];
    }
}

extern "C" void kernel_launch(void* const* d_in, const int* in_sizes, int n_in,
                              void* d_out, int out_size, void* d_ws, size_t ws_size,
                              hipStream_t stream) {
    const float* X  = (const float*)d_in[0];
    const float* Wq = (const float*)d_in[1];
    const float* bq = (const float*)d_in[2];
    const float* Wk = (const float*)d_in[3];
    const float* bk = (const float*)d_in[4];
    const float* Wv = (const float*)d_in[5];
    const float* bv = (const float*)d_in[6];

    float* ctx   = (float*)d_out;
    float* probs = ctx + (size_t)B_ * S_ * D_;

    // bf16 staging of X/W lives in the (later overwritten) probs region of d_out
    unsigned short* Xb = (unsigned short*)probs;            // 14.35 MB
    unsigned short* Wb = Xb + (size_t)MP * 768;             //  3.54 MB

    unsigned short* Qf = (unsigned short*)d_ws;             // 15.7 MB each
    unsigned short* Kf = Qf + (size_t)7864320;
    unsigned short* Vf = Kf + (size_t)7864320;

    prep<<<dim3(1024), 256, 0, stream>>>(X, Wq, Wk, Wv, Xb, Wb);
    qkv_gemm<<<dim3(73, 18), 256, 0, stream>>>(Xb, Wb, bq, bk, bv, Qf, Kf, Vf);
    attn<<<dim3(7104), 256, 0, stream>>>(Qf, Kf, Vf, ctx, probs);
}

// Round 5
// 212.995 us; speedup vs baseline: 2.0383x; 1.0108x over previous
//
#include <hip/hip_runtime.h>
#include <hip/hip_bf16.h>
#include <cstdint>

#define B_  16
#define S_  577
#define D_  768
#define H_  12
#define SP  640           // padded S
#define M_  (B_*S_)       // 9232
#define MP  9344          // padded M (73*128)
#define N_  2304          // combined QKV output dim
#define SCS 664           // sc LDS stride in shorts
#define QSCALE 0.18033688011112042f   // 0.125 * log2(e): scores land in log2 domain

typedef __attribute__((ext_vector_type(8))) short short8;
typedef __attribute__((ext_vector_type(4))) float f32x4;

static __device__ __forceinline__ unsigned short f2bf(float f) {
    uint32_t u = __builtin_bit_cast(uint32_t, f);
    uint32_t r = u + 0x7fffu + ((u >> 16) & 1u);
    return (unsigned short)(r >> 16);
}
static __device__ __forceinline__ float bf2f(unsigned short u) {
    uint32_t x = ((uint32_t)u) << 16;
    return __builtin_bit_cast(float, x);
}

typedef unsigned int u32;
typedef __attribute__((address_space(3))) u32 lds_u32;
typedef __attribute__((address_space(1))) const u32 gbl_u32;
static __device__ __forceinline__ void gll16(const void* g, void* l) {
    __builtin_amdgcn_global_load_lds((gbl_u32*)g, (lds_u32*)l, 16, 0, 0);
}

// Fragment layouts (shorts), d = within-head dim (0..63):
//  Qf: (((b*40+qc)*12+h)*2+dh)*512 + ql*32 + dg*8 + db      q=qc*16+ql, d=dh*32+dg*8+db
//  Kf: (((b*12+h)*10+c)*4+kq)*2+dh)*512 + kl*32 + dg*8 + db key=c*64+kq*16+kl
//  Vf: ((b*12+h)*20+kk)*4+wq)*512 + dl*32 + kg*8 + kb       key=kk*32+kg*8+kb, d=wq*16+dl
// Each attn wave fragment load = contiguous 1KB.

// ---------- prep: fp32 -> bf16 of X (zero pad rows) and W; zero Vf pad keys ----------
__global__ __launch_bounds__(256) void prep(
    const float* __restrict__ X,
    const float* __restrict__ Wq, const float* __restrict__ Wk, const float* __restrict__ Wv,
    unsigned short* __restrict__ Xb, unsigned short* __restrict__ Wb,
    unsigned short* __restrict__ Vf)
{
    const int NT1 = MP * 192;
    const int NT2 = N_ * 192;
    const int VPAD = 192 * 64 * 63;            // (b*h) * d * padkeys
    const int total = NT1 + NT2 + VPAD;
    const int stride = gridDim.x * 256;
    for (int i = blockIdx.x * 256 + threadIdx.x; i < total; i += stride) {
        if (i < NT1) {
            int row = i / 192, c4 = i - row * 192;
            uint2 out = make_uint2(0u, 0u);
            if (row < M_) {
                float4 v = *(const float4*)(X + (size_t)row * 768 + c4 * 4);
                unsigned short p[4] = { f2bf(v.x), f2bf(v.y), f2bf(v.z), f2bf(v.w) };
                out = *(uint2*)p;
            }
            *(uint2*)(Xb + (size_t)row * 768 + c4 * 4) = out;
        } else if (i < NT1 + NT2) {
            int j = i - NT1;
            int row = j / 192, c4 = j - row * 192;
            const float* src = (row < 768) ? (Wq + (size_t)row * 768)
                             : (row < 1536) ? (Wk + (size_t)(row - 768) * 768)
                                            : (Wv + (size_t)(row - 1536) * 768);
            float4 v = *(const float4*)(src + c4 * 4);
            unsigned short p[4] = { f2bf(v.x), f2bf(v.y), f2bf(v.z), f2bf(v.w) };
            *(uint2*)(Wb + (size_t)row * 768 + c4 * 4) = *(uint2*)p;
        } else {
            int j = i - NT1 - NT2;
            int bh = j / (64 * 63), rem = j - bh * (64 * 63);
            int d = rem / 63, key = 577 + (rem - d * 63);
            size_t off = (((size_t)bh * 20 + (key >> 5)) * 4 + (d >> 4)) * 512
                       + (d & 15) * 32 + ((key >> 3) & 3) * 8 + (key & 7);
            Vf[off] = 0;
        }
    }
}

// ---------- qkv_gemm: BK=64, swizzled LDS; Q/K blocks use swapped (A=W) MFMA ----------
__global__ __launch_bounds__(256) void qkv_gemm(
    const unsigned short* __restrict__ Xb, const unsigned short* __restrict__ Wb,
    const float* __restrict__ bq, const float* __restrict__ bk, const float* __restrict__ bv,
    unsigned short* __restrict__ Qf, unsigned short* __restrict__ Kf,
    unsigned short* __restrict__ Vf)
{
    __shared__ unsigned short Als[128 * 64];
    __shared__ unsigned short Bls[128 * 64];

    const int mt = blockIdx.x, nt = blockIdx.y;
    const bool qk = (nt < 12);
    const int tid = threadIdx.x, lane = tid & 63, wid = tid >> 6;
    const int wm = wid >> 1, wn = wid & 1;
    const int m0 = mt * 128, n0 = nt * 128;
    const int l15 = lane & 15, g = lane >> 4;
    const int prow = lane >> 3, pc8 = lane & 7;

    const unsigned short* Pa = qk ? Bls : Als;   // A-operand rows (W for Q/K, X for V)
    const unsigned short* Pb = qk ? Als : Bls;

    f32x4 acc[4][4] = {};

    for (int kk = 0; kk < 768; kk += 64) {
        __syncthreads();
        #pragma unroll
        for (int t = 0; t < 4; ++t) {
            int row  = wid * 32 + t * 8 + prow;
            int scol = ((pc8 ^ (row & 7)) * 8);
            gll16(Xb + (size_t)(m0 + row) * 768 + kk + scol, &Als[(wid * 32 + t * 8) * 64]);
            gll16(Wb + (size_t)(n0 + row) * 768 + kk + scol, &Bls[(wid * 32 + t * 8) * 64]);
        }
        __syncthreads();

        #pragma unroll
        for (int ks = 0; ks < 2; ++ks) {
            short8 fa[4], fb[4];
            #pragma unroll
            for (int i = 0; i < 4; ++i) {
                int row = wm * 64 + i * 16 + l15;
                fa[i] = *(const short8*)&Pa[row * 64 + (((ks * 4 + g) ^ (row & 7)) * 8)];
            }
            #pragma unroll
            for (int j = 0; j < 4; ++j) {
                int row = wn * 64 + j * 16 + l15;
                fb[j] = *(const short8*)&Pb[row * 64 + (((ks * 4 + g) ^ (row & 7)) * 8)];
            }
            #pragma unroll
            for (int i = 0; i < 4; ++i)
                #pragma unroll
                for (int j = 0; j < 4; ++j)
                    acc[i][j] = __builtin_amdgcn_mfma_f32_16x16x32_bf16(fa[i], fb[j], acc[i][j], 0, 0, 0);
        }
    }

    if (qk) {
        // D rows = n (d-dim), cols = m. Pack 4 consecutive d per uint2 store.
        const float* bb = (nt < 6) ? bq : bk;
        unsigned short* Dst = (nt < 6) ? Qf : Kf;
        const float scale = (nt < 6) ? QSCALE : 1.0f;
        #pragma unroll
        for (int i = 0; i < 4; ++i) {
            int nrow0 = n0 - ((nt < 6) ? 0 : 768) + wm * 64 + i * 16 + g * 4;  // 4-aligned
            float4 b4 = *(const float4*)(bb + nrow0);
            int hh = nrow0 >> 6, d0 = nrow0 & 63;
            int dh5 = d0 >> 5;
            int dsub = ((d0 >> 3) & 3) * 8 + (d0 & 7);
            #pragma unroll
            for (int j = 0; j < 4; ++j) {
                int m = m0 + wn * 64 + j * 16 + l15;
                if (m >= M_) continue;
                int b = m / 577, s = m - b * 577;
                unsigned short p[4];
                p[0] = f2bf((acc[i][j][0] + b4.x) * scale);
                p[1] = f2bf((acc[i][j][1] + b4.y) * scale);
                p[2] = f2bf((acc[i][j][2] + b4.z) * scale);
                p[3] = f2bf((acc[i][j][3] + b4.w) * scale);
                size_t off;
                if (nt < 6)
                    off = (((size_t)(b * 40 + (s >> 4)) * 12 + hh) * 2 + dh5) * 512
                        + (s & 15) * 32 + dsub;
                else
                    off = ((((size_t)(b * 12 + hh)) * 10 + (s >> 6)) * 8 + ((s >> 4) & 3) * 2 + dh5) * 512
                        + (s & 15) * 32 + dsub;
                *(uint2*)(Dst + off) = *(uint2*)p;
            }
        }
    } else {
        // V: D rows = m (s), cols = n (d); scatter shorts into Vf
        #pragma unroll
        for (int j = 0; j < 4; ++j) {
            int n = n0 + wn * 64 + j * 16 + l15;
            int nn = n - 1536;
            float bias = bv[nn];
            int hh = nn >> 6, dwh = nn & 63;
            #pragma unroll
            for (int i = 0; i < 4; ++i) {
                #pragma unroll
                for (int r = 0; r < 4; ++r) {
                    int m = m0 + wm * 64 + i * 16 + g * 4 + r;
                    if (m >= M_) continue;
                    int b = m / 577, s = m - b * 577;
                    float val = acc[i][j][r] + bias;
                    size_t off = (((size_t)(b * 12 + hh) * 20 + (s >> 5)) * 4 + (dwh >> 4)) * 512
                               + (dwh & 15) * 32 + ((s >> 3) & 3) * 8 + (s & 7);
                    Vf[off] = f2bf(val);
                }
            }
        }
    }
}

// ---------- attn: coalesced fragment loads, XCD swizzle, nontemporal output ----------
__global__ __launch_bounds__(256) void attn(
    const unsigned short* __restrict__ Qf, const unsigned short* __restrict__ Kf,
    const unsigned short* __restrict__ Vf,
    float* __restrict__ ctx, float* __restrict__ probs)
{
    __shared__ unsigned short sc[16 * SCS];
    __shared__ float rowinv[16];

    const int wg  = blockIdx.x;                 // 7104 = 8 * 888, bijective XCD swizzle
    const int idx = (wg & 7) * 888 + (wg >> 3);
    const int bh  = idx / 37;
    const int qt  = idx - bh * 37;
    const int h   = bh % 12, b = bh / 12;

    const int tid = threadIdx.x, lane = tid & 63, wid = tid >> 6;
    const int l15 = lane & 15, g = lane >> 4;
    const int q0 = qt * 16;
    const int lofs = l15 * 32 + g * 8;

    const unsigned short* qb = Qf + ((size_t)(b * 40 + qt) * 12 + h) * 1024 + lofs;
    short8 aq0 = *(const short8*)qb;
    short8 aq1 = *(const short8*)(qb + 512);

    const unsigned short* kb0 = Kf + (size_t)bh * 40960 + wid * 1024 + lofs;
    #pragma unroll
    for (int c = 0; c < 10; ++c) {
        const unsigned short* kb = kb0 + c * 4096;
        short8 bk0 = *(const short8*)kb;
        short8 bk1 = *(const short8*)(kb + 512);
        f32x4 s4 = {};
        s4 = __builtin_amdgcn_mfma_f32_16x16x32_bf16(aq0, bk0, s4, 0, 0, 0);
        s4 = __builtin_amdgcn_mfma_f32_16x16x32_bf16(aq1, bk1, s4, 0, 0, 0);
        int key = c * 64 + wid * 16 + l15;
        #pragma unroll
        for (int r = 0; r < 4; ++r)
            sc[(g * 4 + r) * SCS + key] = (key < S_) ? f2bf(s4[r]) : (unsigned short)0xFF80u; // -inf
    }
    __syncthreads();

    // softmax (log2 domain): 16 threads per row
    const int r = tid >> 4, c0 = tid & 15;
    unsigned short* row = &sc[r * SCS];
    float m = -1e30f;
    #pragma unroll
    for (int i = 0; i < 5; ++i) {
        short8 v = *(const short8*)&row[(c0 + 16 * i) * 8];
        #pragma unroll
        for (int jj = 0; jj < 8; ++jj) m = fmaxf(m, bf2f((unsigned short)v[jj]));
    }
    #pragma unroll
    for (int o = 8; o; o >>= 1) m = fmaxf(m, __shfl_xor(m, o));

    float ssum = 0.f;
    #pragma unroll
    for (int i = 0; i < 5; ++i) {
        short8 v = *(const short8*)&row[(c0 + 16 * i) * 8];
        short8 w;
        #pragma unroll
        for (int jj = 0; jj < 8; ++jj) {
            float e = exp2f(bf2f((unsigned short)v[jj]) - m);
            ssum += e;
            w[jj] = (short)f2bf(e);
        }
        *(short8*)&row[(c0 + 16 * i) * 8] = w;
    }
    #pragma unroll
    for (int o = 8; o; o >>= 1) ssum += __shfl_xor(ssum, o);
    float inv = 1.0f / ssum;
    if (c0 == 0) rowinv[r] = inv;
    __syncthreads();

    // probs write: nontemporal (no L2 pollution), drains under PV
    int q = q0 + r;
    if (q < S_) {
        float* prow = probs + ((size_t)bh * S_ + q) * S_;
        #pragma unroll
        for (int i = 0; i < 5; ++i) {
            int ch = c0 + 16 * i;
            short8 v = *(const short8*)&row[ch * 8];
            if (ch < 72) {
                f32x4 o0, o1;
                o0[0] = bf2f((unsigned short)v[0]) * inv; o0[1] = bf2f((unsigned short)v[1]) * inv;
                o0[2] = bf2f((unsigned short)v[2]) * inv; o0[3] = bf2f((unsigned short)v[3]) * inv;
                o1[0] = bf2f((unsigned short)v[4]) * inv; o1[1] = bf2f((unsigned short)v[5]) * inv;
                o1[2] = bf2f((unsigned short)v[6]) * inv; o1[3] = bf2f((unsigned short)v[7]) * inv;
                __builtin_nontemporal_store(o0, (f32x4*)&prow[ch * 8]);
                __builtin_nontemporal_store(o1, (f32x4*)&prow[ch * 8 + 4]);
            } else if (ch == 72) {
                __builtin_nontemporal_store(bf2f((unsigned short)v[0]) * inv, &prow[576]);
            }
        }
    }

    // PV: wave wid owns d-slice [wid*16, wid*16+16)
    f32x4 oc = {};
    const unsigned short* vb0 = Vf + (size_t)bh * 40960 + wid * 512 + lofs;
    const unsigned short* pb  = &sc[l15 * SCS + g * 8];
    #pragma unroll
    for (int kk = 0; kk < 20; ++kk) {
        short8 ap = *(const short8*)(pb + kk * 32);
        short8 bv = *(const short8*)(vb0 + kk * 2048);
        oc = __builtin_amdgcn_mfma_f32_16x16x32_bf16(ap, bv, oc, 0, 0, 0);
    }
    #pragma unroll
    for (int rr = 0; rr < 4; ++rr) {
        int qr = g * 4 + rr;
        int qq = q0 + qr;
        if (qq < S_)
            __builtin_nontemporal_store(oc[rr] * rowinv[qr],
                &ctx[((size_t)b * S_ + qq) * D_ + h * 64 + wid * 16 + l15]);
    }
}

extern "C" void kernel_launch(void* const* d_in, const int* in_sizes, int n_in,
                              void* d_out, int out_size, void* d_ws, size_t ws_size,
                              hipStream_t stream) {
    const float* X  = (const float*)d_in[0];
    const float* Wq = (const float*)d_in[1];
    const float* bq = (const float*)d_in[2];
    const float* Wk = (const float*)d_in[3];
    const float* bk = (const float*)d_in[4];
    const float* Wv = (const float*)d_in[5];
    const float* bv = (const float*)d_in[6];

    float* ctx   = (float*)d_out;
    float* probs = ctx + (size_t)B_ * S_ * D_;

    unsigned short* Xb = (unsigned short*)probs;            // staged in probs region
    unsigned short* Wb = Xb + (size_t)MP * 768;

    unsigned short* Qf = (unsigned short*)d_ws;
    unsigned short* Kf = Qf + (size_t)7864320;
    unsigned short* Vf = Kf + (size_t)7864320;

    prep<<<dim3(1024), 256, 0, stream>>>(X, Wq, Wk, Wv, Xb, Wb, Vf);
    qkv_gemm<<<dim3(73, 18), 256, 0, stream>>>(Xb, Wb, bq, bk, bv, Qf, Kf, Vf);
    attn<<<dim3(7104), 256, 0, stream>>>(Qf, Kf, Vf, ctx, probs);
}